// Round 8
// baseline (548.677 us; speedup 1.0000x reference)
//
#include <hip/hip_runtime.h>

#define S_LEN 2048
#define DM    1024
#define NH    16
#define DH    64
#define BATCH 2
#define S2    ((size_t)S_LEN * S_LEN)

typedef _Float16 half_t;
typedef _Float16 f16x8 __attribute__((ext_vector_type(8)));
typedef _Float16 f16x4 __attribute__((ext_vector_type(4)));
typedef float    f32x4 __attribute__((ext_vector_type(4)));

// =====================================================================
// global->LDS direct (16B/lane). LDS dest wave-linear; XOR swizzle on the
// per-lane GLOBAL address (both-sides-or-neither), reads use the same XOR.
// =====================================================================
__device__ __forceinline__ void gll16(const void* g, void* l) {
  __builtin_amdgcn_global_load_lds(
      (const __attribute__((address_space(1))) void*)g,
      (__attribute__((address_space(3))) void*)l, 16, 0, 0);
}

// 256-thread version (used by gemm_k): 128 rows x 64 f16
__device__ __forceinline__ void stage_gll(half_t* lds, const half_t* src, int stride) {
  const int t = threadIdx.x, w = t >> 6, lane = t & 63;
  const int c1 = lane & 7, r8 = lane >> 3;
#pragma unroll
  for (int it = 0; it < 4; ++it) {
    int r = w * 32 + it * 8 + r8;
    const half_t* g = src + (size_t)r * stride + ((c1 ^ r8) << 3);
    gll16(g, lds + (size_t)w * 2048 + it * 512);
  }
}

// per-wave 32 rows x 128 cols over K=64 (4-wave kernels)
__device__ __forceinline__ void mfma_block(const half_t* At, const half_t* Bt,
                                           int w, int lane, f32x4 acc[2][8]) {
  const int grp = lane >> 4, li = lane & 15;
#pragma unroll
  for (int ks = 0; ks < 2; ++ks) {
    const int chunk = ks * 4 + grp;
    f16x8 a[2], b[8];
#pragma unroll
    for (int fr = 0; fr < 2; ++fr) {
      int r = w * 32 + fr * 16 + li;
      a[fr] = *(const f16x8*)&At[(size_t)(r * 8 + (chunk ^ (r & 7))) * 8];
    }
#pragma unroll
    for (int fc = 0; fc < 8; ++fc) {
      int r = fc * 16 + li;
      b[fc] = *(const f16x8*)&Bt[(size_t)(r * 8 + (chunk ^ (r & 7))) * 8];
    }
#pragma unroll
    for (int fr = 0; fr < 2; ++fr)
#pragma unroll
      for (int fc = 0; fc < 8; ++fc)
        acc[fr][fc] = __builtin_amdgcn_mfma_f32_16x16x32_f16(a[fr], b[fc], acc[fr][fc], 0, 0, 0);
  }
}

template<typename ST>
__device__ __forceinline__ void load8s(const ST* p, float* o) {
  if constexpr (sizeof(ST) == 2) {
    f16x8 v = *(const f16x8*)p;
#pragma unroll
    for (int e = 0; e < 8; ++e) o[e] = (float)v[e];
  } else {
    const float4* q = (const float4*)p;
    float4 a = q[0], b = q[1];
    o[0]=a.x; o[1]=a.y; o[2]=a.z; o[3]=a.w; o[4]=b.x; o[5]=b.y; o[6]=b.z; o[7]=b.w;
  }
}

// =====================================================================
// PREP (merged): blocks [0,8192): activations f32->f16 (+zbuf init);
//                blocks [8192,9472): weight convert+transpose (5 mats).
// =====================================================================
struct PArgs {
  const float* asrc[4]; half_t* adst[4];
  const float* wsrc[5]; half_t* wdst[5];
};

__global__ __launch_bounds__(256) void prep(PArgs pa, half_t* zbuf) {
  __shared__ float T[64][65];
  const int bx = blockIdx.x, t = threadIdx.x;
  if (bx < 8192) {
    if (bx == 0 && t < 8) {
      float4 z = {0.f, 0.f, 0.f, 0.f};
      ((float4*)zbuf)[t] = z;
    }
    const int mat = bx >> 11, blk = bx & 2047;
    const float* s = pa.asrc[mat];
    half_t* d = pa.adst[mat];
    size_t i = ((size_t)blk * 256 + t) * 8;
    float4 v0 = *(const float4*)(s + i), v1 = *(const float4*)(s + i + 4);
    f16x8 h;
    h[0]=(half_t)v0.x; h[1]=(half_t)v0.y; h[2]=(half_t)v0.z; h[3]=(half_t)v0.w;
    h[4]=(half_t)v1.x; h[5]=(half_t)v1.y; h[6]=(half_t)v1.z; h[7]=(half_t)v1.w;
    *(f16x8*)(d + i) = h;
  } else {
    const int idx = bx - 8192;          // 0..1279
    const int z = idx >> 8, rem = idx & 255;
    const int k0 = (rem & 15) * 64, n0 = (rem >> 4) * 64;
    const float* W = pa.wsrc[z];
    half_t* D = pa.wdst[z];
#pragma unroll
    for (int it = 0; it < 4; ++it) {
      int id2 = t + it * 256; int r = id2 >> 4, c4 = (id2 & 15) * 4;
      float4 v = *(const float4*)(W + (size_t)(k0 + r) * DM + n0 + c4);
      T[r][c4] = v.x; T[r][c4 + 1] = v.y; T[r][c4 + 2] = v.z; T[r][c4 + 3] = v.w;
    }
    __syncthreads();
#pragma unroll
    for (int it = 0; it < 2; ++it) {
      int id2 = t + it * 256; int n = id2 >> 3, kc = (id2 & 7) * 8;
      f16x8 o;
#pragma unroll
      for (int e = 0; e < 8; ++e) o[e] = (half_t)T[kc + e][n];
      *(f16x8*)&D[(size_t)(n0 + n) * DM + k0 + kc] = o;
    }
  }
}

// =====================================================================
// GEMM: C[M,1024] = A[M,1024](f16) @ Wt[n][k]^T ; z-indexed operand sets.
// Single-buffered staging, 32 KB LDS -> 5 blocks/CU (TLP > explicit dbuf).
// =====================================================================
struct GArgs {
  const half_t* A[4];  const half_t* Bt[4];
  const float* ba[4]; const float* bu[4]; const float* bv[4];
  half_t* oa[4]; half_t* ob[4]; float* of[4];
};

template<bool F32OUT>
__global__ __launch_bounds__(256) void gemm_k(GArgs g, int K) {
  __shared__ __align__(16) half_t At[128 * 64];
  __shared__ __align__(16) half_t Bt[128 * 64];
  const int z = blockIdx.z;
  const half_t* A = g.A[z];
  const half_t* B = g.Bt[z];
  const int n0 = blockIdx.x * 128, m0 = blockIdx.y * 128;
  const int t = threadIdx.x, w = t >> 6, lane = t & 63;
  const f32x4 zf = {0.f, 0.f, 0.f, 0.f};
  f32x4 acc[2][8];
#pragma unroll
  for (int i = 0; i < 2; ++i)
#pragma unroll
    for (int j = 0; j < 8; ++j) acc[i][j] = zf;

  for (int k0 = 0; k0 < K; k0 += 64) {
    stage_gll(At, A + (size_t)m0 * K + k0, K);
    stage_gll(Bt, B + (size_t)n0 * K + k0, K);
    __syncthreads();
    mfma_block(At, Bt, w, lane, acc);
    __syncthreads();
  }
  const int grp = lane >> 4, li = lane & 15;
#pragma unroll
  for (int fr = 0; fr < 2; ++fr)
#pragma unroll
    for (int fc = 0; fc < 8; ++fc)
#pragma unroll
      for (int r = 0; r < 4; ++r) {
        int row = m0 + w * 32 + fr * 16 + grp * 4 + r;
        int col = n0 + fc * 16 + li;
        float v = acc[fr][fc][r];
        if (g.ba[z]) v += g.ba[z][col];
        if constexpr (F32OUT) {
          g.of[z][(size_t)row * DM + col] = v;
        } else {
          float v1 = v + (g.bu[z] ? g.bu[z][col] : 0.f);
          g.oa[z][(size_t)row * DM + col] = (half_t)v1;
          if (g.ob[z]) g.ob[z][(size_t)row * DM + col] = (half_t)(v + g.bv[z][col]);
        }
      }
}

// =====================================================================
// V transpose per head: vp[b*S+s][h*64+d] -> vT[bh][d][s]  (f16)
// =====================================================================
__global__ __launch_bounds__(256) void vtrans(const half_t* vp, half_t* vT) {
  __shared__ half_t T[64][72];
  const int s0 = blockIdx.x * 64, h = blockIdx.y, b = blockIdx.z;
  const int t = threadIdx.x;
#pragma unroll
  for (int it = 0; it < 2; ++it) {
    int idx = t + it * 256; int s = idx >> 3, c = idx & 7;
    uint4 v = *(const uint4*)(vp + ((size_t)(b * S_LEN + s0 + s)) * DM + h * DH + c * 8);
    *(uint4*)&T[s][c * 8] = v;
  }
  __syncthreads();
  half_t* dst = vT + ((size_t)(b * NH + h)) * DH * S_LEN;
#pragma unroll
  for (int it = 0; it < 2; ++it) {
    int idx = t + it * 256; int d = idx >> 3, sc = (idx & 7) * 8;
    f16x8 o;
#pragma unroll
    for (int e = 0; e < 8; ++e) o[e] = T[sc + e][d];
    *(f16x8*)&dst[(size_t)d * S_LEN + s0 + sc] = o;
  }
}

// =====================================================================
// FUSED scores: writes EXP(s) once (f16), s = (content + shifted pos)/32,
// + per-(row, k-tile) sumexp partials (max-free: |s| <~ 3).
//
// TXL shift identity (local q,k in [0,128), base = 1920 + k0 - i0):
//   e = k - q + 127; jvirt = base + e; j = jvirt mod (S+1);
//   delta = (jvirt >= S+1); rel[q,k] = qv[i0+q+delta] . p[j]
//   (virtual row j==S is a zero row -> diagonal zero falls out)
//
// 80KB LDS exactly -> 2 blocks/CU. RegA: phase1 {QU|Kt|Pb}, phase2 Mf full.
// Row rM=128: A-operand from registers; results embedded in Mf's
// unconsumed (ec==15, li==15) slots.
// =====================================================================
template<typename ST>
__global__ __launch_bounds__(512, 4) void score_fused(
    const half_t* __restrict__ qu_, const half_t* __restrict__ qv_,
    const half_t* __restrict__ kp_, const half_t* __restrict__ pp_,
    const half_t* __restrict__ zbuf, ST* __restrict__ sc, float* __restrict__ part)
{
  __shared__ __align__(16) half_t RegA[32768];  // 64 KB
  __shared__ __align__(16) half_t QV[128 * 64]; // 16 KB
  half_t* QU = RegA;            // phase 1
  half_t* Kt = RegA + 8192;
  half_t* Pb = RegA + 16384;
  half_t* Mf = RegA;            // phase 2: full 32768 halfs

  const int bh = blockIdx.z, b = bh >> 4, h = bh & 15;
  const int kt = blockIdx.x, qt = blockIdx.y;
  const int i0 = qt * 128, k0 = kt * 128;
  const int base = 1920 + k0 - i0;              // in [0,3840]
  const int t = threadIdx.x, w = t >> 6, lane = t & 63;
  const int grp = lane >> 4, li = lane & 15;

  // ---- stage QU, Kt, QV (128x64 each), P band (256x64) ----
  {
    const half_t* srcA = qu_ + ((size_t)(b * S_LEN + i0)) * DM + h * DH;
    const half_t* srcB = kp_ + ((size_t)(b * S_LEN + k0)) * DM + h * DH;
    const half_t* srcQ = qv_ + ((size_t)(b * S_LEN + i0)) * DM + h * DH;
#pragma unroll
    for (int p = 0; p < 2; ++p) {
      int cidx = t + p * 512; int r = cidx >> 3, c = cidx & 7;
      size_t off = (size_t)r * DM + ((c ^ (r & 7)) << 3);
      gll16(srcA + off, QU + (size_t)cidx * 8);
      gll16(srcB + off, Kt + (size_t)cidx * 8);
      gll16(srcQ + off, QV + (size_t)cidx * 8);
    }
  }
#pragma unroll
  for (int p = 0; p < 4; ++p) {                 // P band, modular gather + zero row
    int cidx = t + p * 512; int e = cidx >> 3, c = cidx & 7;
    int jv = base + e; if (jv >= S_LEN + 1) jv -= (S_LEN + 1);
    const half_t* src = (jv == S_LEN)
        ? (zbuf + ((c ^ (e & 7)) << 3))
        : (pp_ + ((size_t)(b * S_LEN + jv)) * DM + h * DH + ((c ^ (e & 7)) << 3));
    gll16(src, Pb + (size_t)cidx * 8);
  }

  // qv row i0+128 -> registers (chunk kk*4+grp; linear = deswizzled A-frag).
  f16x8 aq[2];
  {
    int r128 = i0 + 128; if (r128 > S_LEN - 1) r128 = S_LEN - 1;
    const half_t* q128p = qv_ + ((size_t)(b * S_LEN + r128)) * DM + h * DH;
    aq[0] = *(const f16x8*)(q128p + (0 * 4 + grp) * 8);
    aq[1] = *(const f16x8*)(q128p + (1 * 4 + grp) * 8);
  }
  __syncthreads();

  // ---- content MFMA (reads QU,Kt) + bm loads (reads Pb) ----
  const f32x4 zf = {0.f, 0.f, 0.f, 0.f};
  f32x4 acc_c[8];
#pragma unroll
  for (int j = 0; j < 8; ++j) acc_c[j] = zf;
#pragma unroll
  for (int kk = 0; kk < 2; ++kk) {
    const int chunk = kk * 4 + grp;
    int ra = w * 16 + li;
    f16x8 a = *(const f16x8*)&QU[(size_t)(ra * 8 + (chunk ^ (ra & 7))) * 8];
#pragma unroll
    for (int fc = 0; fc < 8; ++fc) {
      int rb = fc * 16 + li;
      f16x8 bf = *(const f16x8*)&Kt[(size_t)(rb * 8 + (chunk ^ (rb & 7))) * 8];
      acc_c[fc] = __builtin_amdgcn_mfma_f32_16x16x32_f16(a, bf, acc_c[fc], 0, 0, 0);
    }
  }
  f16x8 bm[2][2];                               // all of Pb register-cached
#pragma unroll
  for (int kk = 0; kk < 2; ++kk)
#pragma unroll
    for (int eci = 0; eci < 2; ++eci) {
      int rb = (w + eci * 8) * 16 + li;
      bm[kk][eci] = *(const f16x8*)&Pb[(size_t)(rb * 8 + ((kk * 4 + grp) ^ (rb & 7))) * 8];
    }
  __syncthreads();   // all QU/Kt/Pb reads done; RegA now writable as Mf

  // ---- pos band MFMA rf=0..7 -> Mf (full-width fragment layout) ----
  for (int rf = 0; rf < 8; ++rf) {
    f32x4 am[2] = {zf, zf};
#pragma unroll
    for (int kk = 0; kk < 2; ++kk) {
      int ra = rf * 16 + li;
      f16x8 a = *(const f16x8*)&QV[(size_t)(ra * 8 + ((kk * 4 + grp) ^ (ra & 7))) * 8];
#pragma unroll
      for (int eci = 0; eci < 2; ++eci)
        am[eci] = __builtin_amdgcn_mfma_f32_16x16x32_f16(a, bm[kk][eci], am[eci], 0, 0, 0);
    }
#pragma unroll
    for (int eci = 0; eci < 2; ++eci) {
      int ec = w + eci * 8;
      if (!(ec == 15 && li == 15)) {            // keep (ec15,li15) slots free
        f16x4 hv;
#pragma unroll
        for (int r = 0; r < 4; ++r) hv[r] = (half_t)am[eci][r];
        *(f16x4*)&Mf[(size_t)(((ec * 8 + rf) * 4 + grp) * 64 + li * 4)] = hv;
      }
    }
  }

  // ---- 9th row-frag (row i0+128): results into free (ec==15,li==15) slots ----
  {
    f32x4 am0 = zf;
#pragma unroll
    for (int kk = 0; kk < 2; ++kk)
      am0 = __builtin_amdgcn_mfma_f32_16x16x32_f16(aq[kk], bm[kk][0], am0, 0, 0, 0);
    if (grp == 0) {
      int e = w * 16 + li;                      // w<8 always (8 waves)
      Mf[(size_t)(((120 + (e >> 4)) * 4 + ((e >> 2) & 3)) * 64 + 60 + (e & 3))] = (half_t)am0[0];
    }
  }
  __syncthreads();

  // ---- shear-combine, write exp(s) once (coalesced), row sumexp partials ----
  ST* sb = sc + (size_t)bh * S2;
  float lsum[4] = {0.f, 0.f, 0.f, 0.f};
#pragma unroll
  for (int fc = 0; fc < 8; ++fc) {
#pragma unroll
    for (int rr = 0; rr < 4; ++rr) {
      int q = w * 16 + grp * 4 + rr;
      int k = fc * 16 + li;
      int e = k - q + 127;                       // [0,254]
      int jv = base + e;
      int dlt = (jv >= S_LEN + 1) ? 1 : 0;
      int rM = q + dlt;                          // [0,128]
      float mval;
      if (rM < 128) {
        int ec = e >> 4, ei = e & 15, rf = rM >> 4, ri = rM & 15;
        mval = (float)Mf[(size_t)(((ec * 8 + rf) * 4 + (ri >> 2)) * 64 + ei * 4 + (ri & 3))];
      } else {                                   // rM==128 -> q==127, e=k<128
        mval = (float)Mf[(size_t)(((120 + (e >> 4)) * 4 + ((e >> 2) & 3)) * 64 + 60 + (e & 3))];
      }
      float s = (acc_c[fc][rr] + mval) * 0.03125f;
      float ev = __expf(s);
      sb[(size_t)(i0 + q) * S_LEN + k0 + k] = (ST)ev;
      lsum[rr] += ev;
    }
  }
#pragma unroll
  for (int rr = 0; rr < 4; ++rr) {
    float v = lsum[rr];
#pragma unroll
    for (int d = 1; d < 16; d <<= 1) v += __shfl_xor(v, d);
    if (li == 0)
      part[((size_t)bh * S_LEN + i0 + w * 16 + grp * 4 + rr) * 16 + kt] = v;
  }
}

// =====================================================================
// Pass 3: combine sumexp partials -> 1/L; stream exp tiles, scale by 1/L,
// write final f32 attn ONCE, and MFMA p@V -> ctx (f16).
// V staging double-buffered (occupancy-neutral: VGPR-limited 4 blk/CU).
// =====================================================================
template<typename ST>
__global__ __launch_bounds__(256) void av_attn(const ST* sc, const half_t* vT, const float* part,
                                               float* attn, half_t* ctx) {
  __shared__ __align__(16) half_t Vt[2][64 * 128];
  __shared__ float Ls[128];
  const int bh = blockIdx.y, b = bh >> 4, h = bh & 15;
  const int q0 = blockIdx.x * 128;
  const int t = threadIdx.x;
  if (t < 128) {
    const float* pp = part + ((size_t)bh * S_LEN + q0 + t) * 16;
    float L = 0.f;
#pragma unroll
    for (int k = 0; k < 16; ++k) L += pp[k];
    Ls[t] = 1.f / L;
  }
  const ST* sb = sc + (size_t)bh * S2;
  float* ab = attn + (size_t)bh * S2;
  const half_t* vb = vT + (size_t)bh * (DH * S_LEN);
  const int w = t >> 6, lane = t & 63, grp = lane >> 4, li = lane & 15;
  const int c1 = lane & 15, d4 = lane >> 4;
  const f32x4 zf = {0.f, 0.f, 0.f, 0.f};
  f32x4 acc[2][4];
#pragma unroll
  for (int i = 0; i < 2; ++i)
#pragma unroll
    for (int j = 0; j < 4; ++j) acc[i][j] = zf;

  // prologue stage kt=0
#pragma unroll
  for (int it = 0; it < 4; ++it) {
    int d = w * 16 + it * 4 + d4;
    gll16(vb + (size_t)d * S_LEN + ((c1 ^ (d & 15)) << 3), Vt[0] + (size_t)w * 2048 + it * 512);
  }
  __syncthreads();
  int cur = 0;

  for (int kt = 0; kt < 16; ++kt) {
    if (kt + 1 < 16) {
#pragma unroll
      for (int it = 0; it < 4; ++it) {
        int d = w * 16 + it * 4 + d4;
        gll16(vb + (size_t)d * S_LEN + (kt + 1) * 128 + ((c1 ^ (d & 15)) << 3),
              Vt[cur ^ 1] + (size_t)w * 2048 + it * 512);
      }
    }
#pragma unroll
    for (int ks = 0; ks < 4; ++ks) {
      f16x8 pa[2];
#pragma unroll
      for (int fr = 0; fr < 2; ++fr) {
        int r128 = w * 32 + fr * 16 + li;
        int row = q0 + r128;
        int col = kt * 128 + ks * 32 + grp * 8;
        float sv[8];
        load8s(&sb[(size_t)row * S_LEN + col], sv);
        float rL = Ls[r128];
#pragma unroll
        for (int e = 0; e < 8; ++e) sv[e] *= rL;
        float4* dst = (float4*)&ab[(size_t)row * S_LEN + col];
        float4 w0 = {sv[0], sv[1], sv[2], sv[3]};
        float4 w1 = {sv[4], sv[5], sv[6], sv[7]};
        dst[0] = w0; dst[1] = w1;
        f16x8 ph;
#pragma unroll
        for (int e = 0; e < 8; ++e) ph[e] = (half_t)sv[e];
        pa[fr] = ph;
      }
      f16x8 bf[4];
#pragma unroll
      for (int fc = 0; fc < 4; ++fc) {
        int d = fc * 16 + li; int chunk = ks * 4 + grp;
        bf[fc] = *(const f16x8*)&Vt[cur][(size_t)(d * 16 + (chunk ^ (d & 15))) * 8];
      }
#pragma unroll
      for (int fr = 0; fr < 2; ++fr)
#pragma unroll
        for (int fc = 0; fc < 4; ++fc)
          acc[fr][fc] = __builtin_amdgcn_mfma_f32_16x16x32_f16(pa[fr], bf[fc], acc[fr][fc], 0, 0, 0);
    }
    __syncthreads();   // drains stage of kt+1; one barrier/iter
    cur ^= 1;
  }
#pragma unroll
  for (int fr = 0; fr < 2; ++fr)
#pragma unroll
    for (int fc = 0; fc < 4; ++fc)
#pragma unroll
      for (int r = 0; r < 4; ++r) {
        int q = q0 + w * 32 + fr * 16 + grp * 4 + r;
        int d = fc * 16 + li;
        ctx[((size_t)(b * S_LEN + q)) * DM + h * DH + d] = (half_t)acc[fr][fc][r];
      }
}

// =====================================================================
extern "C" void kernel_launch(void* const* d_in, const int* in_sizes, int n_in,
                              void* d_out, int out_size, void* d_ws, size_t ws_size,
                              hipStream_t stream) {
  (void)in_sizes; (void)n_in; (void)out_size;

  const float* query  = (const float*)d_in[0];
  const float* key    = (const float*)d_in[1];
  const float* value  = (const float*)d_in[2];
  const float* pos    = (const float*)d_in[3];
  const float* Wq     = (const float*)d_in[4];
  const float* bq     = (const float*)d_in[5];
  const float* Wk     = (const float*)d_in[6];
  const float* bk     = (const float*)d_in[7];
  const float* Wv     = (const float*)d_in[8];
  const float* bv     = (const float*)d_in[9];
  const float* Wpos   = (const float*)d_in[10];
  const float* u_bias = (const float*)d_in[11];  // [16,64] == flat [1024]
  const float* v_bias = (const float*)d_in[12];
  const float* Wout   = (const float*)d_in[13];
  const float* bout   = (const float*)d_in[14];

  float* out  = (float*)d_out;
  float* attn = out + (size_t)BATCH * S_LEN * DM;

  char* ws = (char*)d_ws;
  half_t* Wt   = (half_t*)(ws);                 // 5 x 1024x1024 f16 = 10,485,760 B
  half_t* Af16 = (half_t*)(ws + 10485760);      // 4 x 8,388,608 B (dead after proj)
  float*  part = (float*)(ws + 10485760);       // 4 MB, aliases Af16 post-proj
  half_t* qu   = (half_t*)(ws + 44040192);
  half_t* qv   = (half_t*)(ws + 52428800);
  half_t* kp   = (half_t*)(ws + 60817408);
  half_t* pp   = (half_t*)(ws + 69206016);
  half_t* vp   = (half_t*)(ws + 77594624);
  half_t* vT   = (half_t*)(ws + 85983232);
  half_t* ctx  = (half_t*)(ws + 77594624);      // alias vp (dead after vtrans)
  half_t* zbuf = (half_t*)(ws + 94371840);      // 128 B zero row
  half_t* scH  = (half_t*)(ws + 94375936);      // 268,435,456 B if it fits
  const bool fast = ws_size >= (size_t)94375936 + (size_t)BATCH * NH * S2 * 2;

  dim3 blk(256);

  // 0. prep: activations -> f16 + zbuf init + weights -> f16 transposed
  PArgs pa;
  pa.asrc[0] = query; pa.asrc[1] = key; pa.asrc[2] = value; pa.asrc[3] = pos;
  for (int i = 0; i < 4; ++i) pa.adst[i] = Af16 + (size_t)i * BATCH * S_LEN * DM;
  pa.wsrc[0] = Wq; pa.wsrc[1] = Wk; pa.wsrc[2] = Wv; pa.wsrc[3] = Wpos; pa.wsrc[4] = Wout;
  for (int i = 0; i < 5; ++i) pa.wdst[i] = Wt + (size_t)i * DM * DM;
  prep<<<dim3(8192 + 1280), blk, 0, stream>>>(pa, zbuf);

  // 1. projections (q dual-output with u/v biases, k, v, p) in one launch
  GArgs ga{};
  for (int i = 0; i < 4; ++i) {
    ga.A[i]  = Af16 + (size_t)i * BATCH * S_LEN * DM;
    ga.Bt[i] = Wt + (size_t)i * DM * DM;
  }
  ga.ba[0] = bq; ga.ba[1] = bk; ga.ba[2] = bv; ga.ba[3] = nullptr;
  ga.bu[0] = u_bias; ga.bv[0] = v_bias;
  ga.oa[0] = qu; ga.oa[1] = kp; ga.oa[2] = vp; ga.oa[3] = pp;
  ga.ob[0] = qv;
  gemm_k<false><<<dim3(8, 32, 4), blk, 0, stream>>>(ga, DM);

  // 2. V -> per-head transposed [bh][d][s]
  vtrans<<<dim3(32, 16, 2), blk, 0, stream>>>(vp, vT);

  // 3. fused scores (content + band pos + shear, exp stored), 4. attn + PV
  dim3 g_sc(16, 16, 32);
  dim3 blk5(512);
  if (fast) {
    score_fused<half_t><<<g_sc, blk5, 0, stream>>>(qu, qv, kp, pp, zbuf, scH, part);
    av_attn<half_t><<<dim3(16, 32), blk, 0, stream>>>(scH, vT, part, attn, ctx);
  } else {
    float* scF = attn;  // f32 exp-scores in-place in the attn output region
    score_fused<float><<<g_sc, blk5, 0, stream>>>(qu, qv, kp, pp, zbuf, scF, part);
    av_attn<float><<<dim3(16, 32), blk, 0, stream>>>(scF, vT, part, attn, ctx);
  }

  // 5. out = ctx @ Wout^T + bout  (f32 output)
  GArgs go{};
  go.A[0] = ctx; go.Bt[0] = Wt + (size_t)4 * DM * DM;
  go.ba[0] = bout; go.of[0] = out;
  gemm_k<true><<<dim3(8, 32, 1), blk, 0, stream>>>(go, DM);
}

// Round 9
// 548.068 us; speedup vs baseline: 1.0011x; 1.0011x over previous
//
#include <hip/hip_runtime.h>

#define S_LEN 2048
#define DM    1024
#define NH    16
#define DH    64
#define BATCH 2
#define S2    ((size_t)S_LEN * S_LEN)
#define CTXSZ ((size_t)BATCH * S_LEN * DM)

typedef _Float16 half_t;
typedef _Float16 f16x8 __attribute__((ext_vector_type(8)));
typedef _Float16 f16x4 __attribute__((ext_vector_type(4)));
typedef float    f32x4 __attribute__((ext_vector_type(4)));

// =====================================================================
// global->LDS direct (16B/lane). LDS dest wave-linear; XOR swizzle on the
// per-lane GLOBAL address (both-sides-or-neither), reads use the same XOR.
// =====================================================================
__device__ __forceinline__ void gll16(const void* g, void* l) {
  __builtin_amdgcn_global_load_lds(
      (const __attribute__((address_space(1))) void*)g,
      (__attribute__((address_space(3))) void*)l, 16, 0, 0);
}

// 256-thread version (used by gemm_k): 128 rows x 64 f16
__device__ __forceinline__ void stage_gll(half_t* lds, const half_t* src, int stride) {
  const int t = threadIdx.x, w = t >> 6, lane = t & 63;
  const int c1 = lane & 7, r8 = lane >> 3;
#pragma unroll
  for (int it = 0; it < 4; ++it) {
    int r = w * 32 + it * 8 + r8;
    const half_t* g = src + (size_t)r * stride + ((c1 ^ r8) << 3);
    gll16(g, lds + (size_t)w * 2048 + it * 512);
  }
}

// per-wave 32 rows x 128 cols over K=64 (4-wave kernels)
__device__ __forceinline__ void mfma_block(const half_t* At, const half_t* Bt,
                                           int w, int lane, f32x4 acc[2][8]) {
  const int grp = lane >> 4, li = lane & 15;
#pragma unroll
  for (int ks = 0; ks < 2; ++ks) {
    const int chunk = ks * 4 + grp;
    f16x8 a[2], b[8];
#pragma unroll
    for (int fr = 0; fr < 2; ++fr) {
      int r = w * 32 + fr * 16 + li;
      a[fr] = *(const f16x8*)&At[(size_t)(r * 8 + (chunk ^ (r & 7))) * 8];
    }
#pragma unroll
    for (int fc = 0; fc < 8; ++fc) {
      int r = fc * 16 + li;
      b[fc] = *(const f16x8*)&Bt[(size_t)(r * 8 + (chunk ^ (r & 7))) * 8];
    }
#pragma unroll
    for (int fr = 0; fr < 2; ++fr)
#pragma unroll
      for (int fc = 0; fc < 8; ++fc)
        acc[fr][fc] = __builtin_amdgcn_mfma_f32_16x16x32_f16(a[fr], b[fc], acc[fr][fc], 0, 0, 0);
  }
}

template<typename ST>
__device__ __forceinline__ void load8s(const ST* p, float* o) {
  if constexpr (sizeof(ST) == 2) {
    f16x8 v = *(const f16x8*)p;
#pragma unroll
    for (int e = 0; e < 8; ++e) o[e] = (float)v[e];
  } else {
    const float4* q = (const float4*)p;
    float4 a = q[0], b = q[1];
    o[0]=a.x; o[1]=a.y; o[2]=a.z; o[3]=a.w; o[4]=b.x; o[5]=b.y; o[6]=b.z; o[7]=b.w;
  }
}

// =====================================================================
// PREP (merged): blocks [0,8192): activations f32->f16 (+zbuf init);
//                blocks [8192,9472): weight convert+transpose (5 mats).
// =====================================================================
struct PArgs {
  const float* asrc[4]; half_t* adst[4];
  const float* wsrc[5]; half_t* wdst[5];
};

__global__ __launch_bounds__(256) void prep(PArgs pa, half_t* zbuf) {
  __shared__ float T[64][65];
  const int bx = blockIdx.x, t = threadIdx.x;
  if (bx < 8192) {
    if (bx == 0 && t < 8) {
      float4 z = {0.f, 0.f, 0.f, 0.f};
      ((float4*)zbuf)[t] = z;
    }
    const int mat = bx >> 11, blk = bx & 2047;
    const float* s = pa.asrc[mat];
    half_t* d = pa.adst[mat];
    size_t i = ((size_t)blk * 256 + t) * 8;
    float4 v0 = *(const float4*)(s + i), v1 = *(const float4*)(s + i + 4);
    f16x8 h;
    h[0]=(half_t)v0.x; h[1]=(half_t)v0.y; h[2]=(half_t)v0.z; h[3]=(half_t)v0.w;
    h[4]=(half_t)v1.x; h[5]=(half_t)v1.y; h[6]=(half_t)v1.z; h[7]=(half_t)v1.w;
    *(f16x8*)(d + i) = h;
  } else {
    const int idx = bx - 8192;          // 0..1279
    const int z = idx >> 8, rem = idx & 255;
    const int k0 = (rem & 15) * 64, n0 = (rem >> 4) * 64;
    const float* W = pa.wsrc[z];
    half_t* D = pa.wdst[z];
#pragma unroll
    for (int it = 0; it < 4; ++it) {
      int id2 = t + it * 256; int r = id2 >> 4, c4 = (id2 & 15) * 4;
      float4 v = *(const float4*)(W + (size_t)(k0 + r) * DM + n0 + c4);
      T[r][c4] = v.x; T[r][c4 + 1] = v.y; T[r][c4 + 2] = v.z; T[r][c4 + 3] = v.w;
    }
    __syncthreads();
#pragma unroll
    for (int it = 0; it < 2; ++it) {
      int id2 = t + it * 256; int n = id2 >> 3, kc = (id2 & 7) * 8;
      f16x8 o;
#pragma unroll
      for (int e = 0; e < 8; ++e) o[e] = (half_t)T[kc + e][n];
      *(f16x8*)&D[(size_t)(n0 + n) * DM + k0 + kc] = o;
    }
  }
}

// =====================================================================
// GEMM: C[M,1024] = A[M,1024](f16) @ Wt[n][k]^T ; z-indexed operand sets.
// Single-buffered staging, 32 KB LDS -> 5 blocks/CU.
// =====================================================================
struct GArgs {
  const half_t* A[4];  const half_t* Bt[4];
  const float* ba[4]; const float* bu[4]; const float* bv[4];
  half_t* oa[4]; half_t* ob[4]; float* of[4];
};

template<bool F32OUT>
__global__ __launch_bounds__(256) void gemm_k(GArgs g, int K) {
  __shared__ __align__(16) half_t At[128 * 64];
  __shared__ __align__(16) half_t Bt[128 * 64];
  const int z = blockIdx.z;
  const half_t* A = g.A[z];
  const half_t* B = g.Bt[z];
  const int n0 = blockIdx.x * 128, m0 = blockIdx.y * 128;
  const int t = threadIdx.x, w = t >> 6, lane = t & 63;
  const f32x4 zf = {0.f, 0.f, 0.f, 0.f};
  f32x4 acc[2][8];
#pragma unroll
  for (int i = 0; i < 2; ++i)
#pragma unroll
    for (int j = 0; j < 8; ++j) acc[i][j] = zf;

  for (int k0 = 0; k0 < K; k0 += 64) {
    stage_gll(At, A + (size_t)m0 * K + k0, K);
    stage_gll(Bt, B + (size_t)n0 * K + k0, K);
    __syncthreads();
    mfma_block(At, Bt, w, lane, acc);
    __syncthreads();
  }
  const int grp = lane >> 4, li = lane & 15;
#pragma unroll
  for (int fr = 0; fr < 2; ++fr)
#pragma unroll
    for (int fc = 0; fc < 8; ++fc)
#pragma unroll
      for (int r = 0; r < 4; ++r) {
        int row = m0 + w * 32 + fr * 16 + grp * 4 + r;
        int col = n0 + fc * 16 + li;
        float v = acc[fr][fc][r];
        if (g.ba[z]) v += g.ba[z][col];
        if constexpr (F32OUT) {
          g.of[z][(size_t)row * DM + col] = v;
        } else {
          float v1 = v + (g.bu[z] ? g.bu[z][col] : 0.f);
          g.oa[z][(size_t)row * DM + col] = (half_t)v1;
          if (g.ob[z]) g.ob[z][(size_t)row * DM + col] = (half_t)(v + g.bv[z][col]);
        }
      }
}

// =====================================================================
// V transpose per head: vp[b*S+s][h*64+d] -> vT[bh][d][s]  (f16)
// =====================================================================
__global__ __launch_bounds__(256) void vtrans(const half_t* vp, half_t* vT) {
  __shared__ half_t T[64][72];
  const int s0 = blockIdx.x * 64, h = blockIdx.y, b = blockIdx.z;
  const int t = threadIdx.x;
#pragma unroll
  for (int it = 0; it < 2; ++it) {
    int idx = t + it * 256; int s = idx >> 3, c = idx & 7;
    uint4 v = *(const uint4*)(vp + ((size_t)(b * S_LEN + s0 + s)) * DM + h * DH + c * 8);
    *(uint4*)&T[s][c * 8] = v;
  }
  __syncthreads();
  half_t* dst = vT + ((size_t)(b * NH + h)) * DH * S_LEN;
#pragma unroll
  for (int it = 0; it < 2; ++it) {
    int idx = t + it * 256; int d = idx >> 3, sc = (idx & 7) * 8;
    f16x8 o;
#pragma unroll
    for (int e = 0; e < 8; ++e) o[e] = T[sc + e][d];
    *(f16x8*)&dst[(size_t)d * S_LEN + s0 + sc] = o;
  }
}

// =====================================================================
// FUSED scores: writes EXP(s) once (f16), s = (content + shifted pos)/32,
// + per-(row, k-tile) sumexp partials (max-free: |s| <~ 3).
//
// TXL shift identity (local q,k in [0,128), base = 1920 + k0 - i0):
//   e = k - q + 127; jvirt = base + e; j = jvirt mod (S+1);
//   delta = (jvirt >= S+1); rel[q,k] = qv[i0+q+delta] . p[j]
//   (virtual row j==S is a zero row -> diagonal zero falls out)
//
// 80KB LDS exactly -> 2 blocks/CU. RegA: phase1 {QU|Kt|Pb}, phase2 Mf full.
// Row rM=128: A-operand from registers; results embedded in Mf's
// unconsumed (ec==15, li==15) slots.
// =====================================================================
template<typename ST>
__global__ __launch_bounds__(512, 4) void score_fused(
    const half_t* __restrict__ qu_, const half_t* __restrict__ qv_,
    const half_t* __restrict__ kp_, const half_t* __restrict__ pp_,
    const half_t* __restrict__ zbuf, ST* __restrict__ sc, float* __restrict__ part)
{
  __shared__ __align__(16) half_t RegA[32768];  // 64 KB
  __shared__ __align__(16) half_t QV[128 * 64]; // 16 KB
  half_t* QU = RegA;            // phase 1
  half_t* Kt = RegA + 8192;
  half_t* Pb = RegA + 16384;
  half_t* Mf = RegA;            // phase 2: full 32768 halfs

  const int bh = blockIdx.z, b = bh >> 4, h = bh & 15;
  const int kt = blockIdx.x, qt = blockIdx.y;
  const int i0 = qt * 128, k0 = kt * 128;
  const int base = 1920 + k0 - i0;              // in [0,3840]
  const int t = threadIdx.x, w = t >> 6, lane = t & 63;
  const int grp = lane >> 4, li = lane & 15;

  // ---- stage QU, Kt, QV (128x64 each), P band (256x64) ----
  {
    const half_t* srcA = qu_ + ((size_t)(b * S_LEN + i0)) * DM + h * DH;
    const half_t* srcB = kp_ + ((size_t)(b * S_LEN + k0)) * DM + h * DH;
    const half_t* srcQ = qv_ + ((size_t)(b * S_LEN + i0)) * DM + h * DH;
#pragma unroll
    for (int p = 0; p < 2; ++p) {
      int cidx = t + p * 512; int r = cidx >> 3, c = cidx & 7;
      size_t off = (size_t)r * DM + ((c ^ (r & 7)) << 3);
      gll16(srcA + off, QU + (size_t)cidx * 8);
      gll16(srcB + off, Kt + (size_t)cidx * 8);
      gll16(srcQ + off, QV + (size_t)cidx * 8);
    }
  }
#pragma unroll
  for (int p = 0; p < 4; ++p) {                 // P band, modular gather + zero row
    int cidx = t + p * 512; int e = cidx >> 3, c = cidx & 7;
    int jv = base + e; if (jv >= S_LEN + 1) jv -= (S_LEN + 1);
    const half_t* src = (jv == S_LEN)
        ? (zbuf + ((c ^ (e & 7)) << 3))
        : (pp_ + ((size_t)(b * S_LEN + jv)) * DM + h * DH + ((c ^ (e & 7)) << 3));
    gll16(src, Pb + (size_t)cidx * 8);
  }

  // qv row i0+128 -> registers (chunk kk*4+grp; linear = deswizzled A-frag).
  f16x8 aq[2];
  {
    int r128 = i0 + 128; if (r128 > S_LEN - 1) r128 = S_LEN - 1;
    const half_t* q128p = qv_ + ((size_t)(b * S_LEN + r128)) * DM + h * DH;
    aq[0] = *(const f16x8*)(q128p + (0 * 4 + grp) * 8);
    aq[1] = *(const f16x8*)(q128p + (1 * 4 + grp) * 8);
  }
  __syncthreads();

  // ---- content MFMA (reads QU,Kt) + bm loads (reads Pb) ----
  const f32x4 zf = {0.f, 0.f, 0.f, 0.f};
  f32x4 acc_c[8];
#pragma unroll
  for (int j = 0; j < 8; ++j) acc_c[j] = zf;
#pragma unroll
  for (int kk = 0; kk < 2; ++kk) {
    const int chunk = kk * 4 + grp;
    int ra = w * 16 + li;
    f16x8 a = *(const f16x8*)&QU[(size_t)(ra * 8 + (chunk ^ (ra & 7))) * 8];
#pragma unroll
    for (int fc = 0; fc < 8; ++fc) {
      int rb = fc * 16 + li;
      f16x8 bf = *(const f16x8*)&Kt[(size_t)(rb * 8 + (chunk ^ (rb & 7))) * 8];
      acc_c[fc] = __builtin_amdgcn_mfma_f32_16x16x32_f16(a, bf, acc_c[fc], 0, 0, 0);
    }
  }
  f16x8 bm[2][2];                               // all of Pb register-cached
#pragma unroll
  for (int kk = 0; kk < 2; ++kk)
#pragma unroll
    for (int eci = 0; eci < 2; ++eci) {
      int rb = (w + eci * 8) * 16 + li;
      bm[kk][eci] = *(const f16x8*)&Pb[(size_t)(rb * 8 + ((kk * 4 + grp) ^ (rb & 7))) * 8];
    }
  __syncthreads();   // all QU/Kt/Pb reads done; RegA now writable as Mf

  // ---- pos band MFMA rf=0..7 -> Mf (full-width fragment layout) ----
  for (int rf = 0; rf < 8; ++rf) {
    f32x4 am[2] = {zf, zf};
#pragma unroll
    for (int kk = 0; kk < 2; ++kk) {
      int ra = rf * 16 + li;
      f16x8 a = *(const f16x8*)&QV[(size_t)(ra * 8 + ((kk * 4 + grp) ^ (ra & 7))) * 8];
#pragma unroll
      for (int eci = 0; eci < 2; ++eci)
        am[eci] = __builtin_amdgcn_mfma_f32_16x16x32_f16(a, bm[kk][eci], am[eci], 0, 0, 0);
    }
#pragma unroll
    for (int eci = 0; eci < 2; ++eci) {
      int ec = w + eci * 8;
      if (!(ec == 15 && li == 15)) {            // keep (ec15,li15) slots free
        f16x4 hv;
#pragma unroll
        for (int r = 0; r < 4; ++r) hv[r] = (half_t)am[eci][r];
        *(f16x4*)&Mf[(size_t)(((ec * 8 + rf) * 4 + grp) * 64 + li * 4)] = hv;
      }
    }
  }

  // ---- 9th row-frag (row i0+128): results into free (ec==15,li==15) slots ----
  {
    f32x4 am0 = zf;
#pragma unroll
    for (int kk = 0; kk < 2; ++kk)
      am0 = __builtin_amdgcn_mfma_f32_16x16x32_f16(aq[kk], bm[kk][0], am0, 0, 0, 0);
    if (grp == 0) {
      int e = w * 16 + li;                      // w<8 always (8 waves)
      Mf[(size_t)(((120 + (e >> 4)) * 4 + ((e >> 2) & 3)) * 64 + 60 + (e & 3))] = (half_t)am0[0];
    }
  }
  __syncthreads();

  // ---- shear-combine, write exp(s) once (coalesced), row sumexp partials ----
  ST* sb = sc + (size_t)bh * S2;
  float lsum[4] = {0.f, 0.f, 0.f, 0.f};
#pragma unroll
  for (int fc = 0; fc < 8; ++fc) {
#pragma unroll
    for (int rr = 0; rr < 4; ++rr) {
      int q = w * 16 + grp * 4 + rr;
      int k = fc * 16 + li;
      int e = k - q + 127;                       // [0,254]
      int jv = base + e;
      int dlt = (jv >= S_LEN + 1) ? 1 : 0;
      int rM = q + dlt;                          // [0,128]
      float mval;
      if (rM < 128) {
        int ec = e >> 4, ei = e & 15, rf = rM >> 4, ri = rM & 15;
        mval = (float)Mf[(size_t)(((ec * 8 + rf) * 4 + (ri >> 2)) * 64 + ei * 4 + (ri & 3))];
      } else {                                   // rM==128 -> q==127, e=k<128
        mval = (float)Mf[(size_t)(((120 + (e >> 4)) * 4 + ((e >> 2) & 3)) * 64 + 60 + (e & 3))];
      }
      float s = (acc_c[fc][rr] + mval) * 0.03125f;
      float ev = __expf(s);
      sb[(size_t)(i0 + q) * S_LEN + k0 + k] = (ST)ev;
      lsum[rr] += ev;
    }
  }
#pragma unroll
  for (int rr = 0; rr < 4; ++rr) {
    float v = lsum[rr];
#pragma unroll
    for (int d = 1; d < 16; d <<= 1) v += __shfl_xor(v, d);
    if (li == 0)
      part[((size_t)bh * S_LEN + i0 + w * 16 + grp * 4 + rr) * 16 + kt] = v;
  }
}

// =====================================================================
// Pass 3 (kt-split x2): combine sumexp partials -> 1/L; stream exp tiles
// for kt in [kz*8,(kz+1)*8), scale by 1/L, write final f32 attn cols,
// MFMA p@V -> PARTIAL ctx (f16) per kz. 4 blocks/CU (vs 2 unsplit).
// =====================================================================
template<typename ST>
__global__ __launch_bounds__(256) void av_attn(const ST* sc, const half_t* vT, const float* part,
                                               float* attn, half_t* ctxp) {
  __shared__ __align__(16) half_t Vt[2][64 * 128];
  __shared__ float Ls[128];
  const int bh = blockIdx.y, b = bh >> 4, h = bh & 15;
  const int q0 = blockIdx.x * 128;
  const int kz = blockIdx.z;
  const int t = threadIdx.x;
  if (t < 128) {
    const float* pp = part + ((size_t)bh * S_LEN + q0 + t) * 16;
    float L = 0.f;
#pragma unroll
    for (int k = 0; k < 16; ++k) L += pp[k];
    Ls[t] = 1.f / L;
  }
  const ST* sb = sc + (size_t)bh * S2;
  float* ab = attn + (size_t)bh * S2;
  const half_t* vb = vT + (size_t)bh * (DH * S_LEN);
  half_t* ctx = ctxp + (size_t)kz * CTXSZ;
  const int w = t >> 6, lane = t & 63, grp = lane >> 4, li = lane & 15;
  const int c1 = lane & 15, d4 = lane >> 4;
  const int kt0 = kz * 8, kt1 = kt0 + 8;
  const f32x4 zf = {0.f, 0.f, 0.f, 0.f};
  f32x4 acc[2][4];
#pragma unroll
  for (int i = 0; i < 2; ++i)
#pragma unroll
    for (int j = 0; j < 4; ++j) acc[i][j] = zf;

  // prologue stage kt0
#pragma unroll
  for (int it = 0; it < 4; ++it) {
    int d = w * 16 + it * 4 + d4;
    gll16(vb + (size_t)d * S_LEN + kt0 * 128 + ((c1 ^ (d & 15)) << 3),
          Vt[0] + (size_t)w * 2048 + it * 512);
  }
  __syncthreads();
  int cur = 0;

  for (int kt = kt0; kt < kt1; ++kt) {
    if (kt + 1 < kt1) {
#pragma unroll
      for (int it = 0; it < 4; ++it) {
        int d = w * 16 + it * 4 + d4;
        gll16(vb + (size_t)d * S_LEN + (kt + 1) * 128 + ((c1 ^ (d & 15)) << 3),
              Vt[cur ^ 1] + (size_t)w * 2048 + it * 512);
      }
    }
#pragma unroll
    for (int ks = 0; ks < 4; ++ks) {
      f16x8 pa[2];
#pragma unroll
      for (int fr = 0; fr < 2; ++fr) {
        int r128 = w * 32 + fr * 16 + li;
        int row = q0 + r128;
        int col = kt * 128 + ks * 32 + grp * 8;
        float sv[8];
        load8s(&sb[(size_t)row * S_LEN + col], sv);
        float rL = Ls[r128];
#pragma unroll
        for (int e = 0; e < 8; ++e) sv[e] *= rL;
        float4* dst = (float4*)&ab[(size_t)row * S_LEN + col];
        float4 w0 = {sv[0], sv[1], sv[2], sv[3]};
        float4 w1 = {sv[4], sv[5], sv[6], sv[7]};
        dst[0] = w0; dst[1] = w1;
        f16x8 ph;
#pragma unroll
        for (int e = 0; e < 8; ++e) ph[e] = (half_t)sv[e];
        pa[fr] = ph;
      }
      f16x8 bf[4];
#pragma unroll
      for (int fc = 0; fc < 4; ++fc) {
        int d = fc * 16 + li; int chunk = ks * 4 + grp;
        bf[fc] = *(const f16x8*)&Vt[cur][(size_t)(d * 16 + (chunk ^ (d & 15))) * 8];
      }
#pragma unroll
      for (int fr = 0; fr < 2; ++fr)
#pragma unroll
        for (int fc = 0; fc < 4; ++fc)
          acc[fr][fc] = __builtin_amdgcn_mfma_f32_16x16x32_f16(pa[fr], bf[fc], acc[fr][fc], 0, 0, 0);
    }
    __syncthreads();   // drains stage of kt+1; one barrier/iter
    cur ^= 1;
  }
#pragma unroll
  for (int fr = 0; fr < 2; ++fr)
#pragma unroll
    for (int fc = 0; fc < 4; ++fc)
#pragma unroll
      for (int r = 0; r < 4; ++r) {
        int q = q0 + w * 32 + fr * 16 + grp * 4 + r;
        int d = fc * 16 + li;
        ctx[((size_t)(b * S_LEN + q)) * DM + h * DH + d] = (half_t)acc[fr][fc][r];
      }
}

// =====================================================================
// Combine the two partial ctx halves: ctx = ctxp[0] + ctxp[1] (f32 math).
// =====================================================================
__global__ __launch_bounds__(256) void combine2(const half_t* a, const half_t* b, half_t* o) {
  size_t i = ((size_t)blockIdx.x * 256 + threadIdx.x) * 8;
  f16x8 va = *(const f16x8*)(a + i);
  f16x8 vb = *(const f16x8*)(b + i);
  f16x8 vo;
#pragma unroll
  for (int e = 0; e < 8; ++e) vo[e] = (half_t)((float)va[e] + (float)vb[e]);
  *(f16x8*)(o + i) = vo;
}

// =====================================================================
extern "C" void kernel_launch(void* const* d_in, const int* in_sizes, int n_in,
                              void* d_out, int out_size, void* d_ws, size_t ws_size,
                              hipStream_t stream) {
  (void)in_sizes; (void)n_in; (void)out_size;

  const float* query  = (const float*)d_in[0];
  const float* key    = (const float*)d_in[1];
  const float* value  = (const float*)d_in[2];
  const float* pos    = (const float*)d_in[3];
  const float* Wq     = (const float*)d_in[4];
  const float* bq     = (const float*)d_in[5];
  const float* Wk     = (const float*)d_in[6];
  const float* bk     = (const float*)d_in[7];
  const float* Wv     = (const float*)d_in[8];
  const float* bv     = (const float*)d_in[9];
  const float* Wpos   = (const float*)d_in[10];
  const float* u_bias = (const float*)d_in[11];  // [16,64] == flat [1024]
  const float* v_bias = (const float*)d_in[12];
  const float* Wout   = (const float*)d_in[13];
  const float* bout   = (const float*)d_in[14];

  float* out  = (float*)d_out;
  float* attn = out + (size_t)BATCH * S_LEN * DM;

  char* ws = (char*)d_ws;
  half_t* Wt   = (half_t*)(ws);                 // 5 x 1024x1024 f16 = 10,485,760 B
  half_t* Af16 = (half_t*)(ws + 10485760);      // 4 x 8,388,608 B (dead after proj)
  float*  part = (float*)(ws + 10485760);       // 4 MB, aliases Af16[0] post-proj
  half_t* ctxp = (half_t*)(ws + 14680064);      // 2 x 16.8MB? no: 2 x 8,388,608 B,
                                                // aliases Af16 tail (dead post-proj)
  half_t* qu   = (half_t*)(ws + 44040192);
  half_t* qv   = (half_t*)(ws + 52428800);
  half_t* kp   = (half_t*)(ws + 60817408);
  half_t* pp   = (half_t*)(ws + 69206016);
  half_t* vp   = (half_t*)(ws + 77594624);
  half_t* vT   = (half_t*)(ws + 85983232);
  half_t* ctx  = (half_t*)(ws + 77594624);      // alias vp (dead after vtrans)
  half_t* zbuf = (half_t*)(ws + 94371840);      // 128 B zero row
  half_t* scH  = (half_t*)(ws + 94375936);      // 268,435,456 B if it fits
  const bool fast = ws_size >= (size_t)94375936 + (size_t)BATCH * NH * S2 * 2;

  dim3 blk(256);

  // 0. prep: activations -> f16 + zbuf init + weights -> f16 transposed
  PArgs pa;
  pa.asrc[0] = query; pa.asrc[1] = key; pa.asrc[2] = value; pa.asrc[3] = pos;
  for (int i = 0; i < 4; ++i) pa.adst[i] = Af16 + (size_t)i * CTXSZ;
  pa.wsrc[0] = Wq; pa.wsrc[1] = Wk; pa.wsrc[2] = Wv; pa.wsrc[3] = Wpos; pa.wsrc[4] = Wout;
  for (int i = 0; i < 5; ++i) pa.wdst[i] = Wt + (size_t)i * DM * DM;
  prep<<<dim3(8192 + 1280), blk, 0, stream>>>(pa, zbuf);

  // 1. projections (q dual-output with u/v biases, k, v, p) in one launch
  GArgs ga{};
  for (int i = 0; i < 4; ++i) {
    ga.A[i]  = Af16 + (size_t)i * CTXSZ;
    ga.Bt[i] = Wt + (size_t)i * DM * DM;
  }
  ga.ba[0] = bq; ga.ba[1] = bk; ga.ba[2] = bv; ga.ba[3] = nullptr;
  ga.bu[0] = u_bias; ga.bv[0] = v_bias;
  ga.oa[0] = qu; ga.oa[1] = kp; ga.oa[2] = vp; ga.oa[3] = pp;
  ga.ob[0] = qv;
  gemm_k<false><<<dim3(8, 32, 4), blk, 0, stream>>>(ga, DM);

  // 2. V -> per-head transposed [bh][d][s]
  vtrans<<<dim3(32, 16, 2), blk, 0, stream>>>(vp, vT);

  // 3. fused scores, 4. attn + PV (kt-split x2), 5. combine partial ctx
  dim3 g_sc(16, 16, 32);
  dim3 blk5(512);
  if (fast) {
    score_fused<half_t><<<g_sc, blk5, 0, stream>>>(qu, qv, kp, pp, zbuf, scH, part);
    av_attn<half_t><<<dim3(16, 32, 2), blk, 0, stream>>>(scH, vT, part, attn, ctxp);
  } else {
    float* scF = attn;  // f32 exp-scores in-place in the attn output region
    score_fused<float><<<g_sc, blk5, 0, stream>>>(qu, qv, kp, pp, zbuf, scF, part);
    av_attn<float><<<dim3(16, 32, 2), blk, 0, stream>>>(scF, vT, part, attn, ctxp);
  }
  combine2<<<dim3((int)(CTXSZ / 8 / 256)), blk, 0, stream>>>(ctxp, ctxp + CTXSZ, ctx);

  // 6. out = ctx @ Wout^T + bout  (f32 output)
  GArgs go{};
  go.A[0] = ctx; go.Bt[0] = Wt + (size_t)4 * DM * DM;
  go.ba[0] = bout; go.of[0] = out;
  gemm_k<true><<<dim3(8, 32, 1), blk, 0, stream>>>(go, DM);
}

// Round 10
// 511.725 us; speedup vs baseline: 1.0722x; 1.0710x over previous
//
#include <hip/hip_runtime.h>

#define S_LEN 2048
#define DM    1024
#define NH    16
#define DH    64
#define BATCH 2
#define S2    ((size_t)S_LEN * S_LEN)
#define CTXSZ ((size_t)BATCH * S_LEN * DM)

typedef _Float16 half_t;
typedef _Float16 f16x8 __attribute__((ext_vector_type(8)));
typedef float    f32x4 __attribute__((ext_vector_type(4)));

// =====================================================================
// global->LDS direct (16B/lane). LDS dest wave-linear; XOR swizzle on the
// per-lane GLOBAL address (both-sides-or-neither), reads use the same XOR.
// =====================================================================
__device__ __forceinline__ void gll16(const void* g, void* l) {
  __builtin_amdgcn_global_load_lds(
      (const __attribute__((address_space(1))) void*)g,
      (__attribute__((address_space(3))) void*)l, 16, 0, 0);
}

// 256-thread version (used by gemm_k): 128 rows x 64 f16
__device__ __forceinline__ void stage_gll(half_t* lds, const half_t* src, int stride) {
  const int t = threadIdx.x, w = t >> 6, lane = t & 63;
  const int c1 = lane & 7, r8 = lane >> 3;
#pragma unroll
  for (int it = 0; it < 4; ++it) {
    int r = w * 32 + it * 8 + r8;
    const half_t* g = src + (size_t)r * stride + ((c1 ^ r8) << 3);
    gll16(g, lds + (size_t)w * 2048 + it * 512);
  }
}

// per-wave 32 rows x 128 cols over K=64 (4-wave kernels)
__device__ __forceinline__ void mfma_block(const half_t* At, const half_t* Bt,
                                           int w, int lane, f32x4 acc[2][8]) {
  const int grp = lane >> 4, li = lane & 15;
#pragma unroll
  for (int ks = 0; ks < 2; ++ks) {
    const int chunk = ks * 4 + grp;
    f16x8 a[2], b[8];
#pragma unroll
    for (int fr = 0; fr < 2; ++fr) {
      int r = w * 32 + fr * 16 + li;
      a[fr] = *(const f16x8*)&At[(size_t)(r * 8 + (chunk ^ (r & 7))) * 8];
    }
#pragma unroll
    for (int fc = 0; fc < 8; ++fc) {
      int r = fc * 16 + li;
      b[fc] = *(const f16x8*)&Bt[(size_t)(r * 8 + (chunk ^ (r & 7))) * 8];
    }
#pragma unroll
    for (int fr = 0; fr < 2; ++fr)
#pragma unroll
      for (int fc = 0; fc < 8; ++fc)
        acc[fr][fc] = __builtin_amdgcn_mfma_f32_16x16x32_f16(a[fr], b[fc], acc[fr][fc], 0, 0, 0);
  }
}

template<typename ST>
__device__ __forceinline__ void load8s(const ST* p, float* o) {
  if constexpr (sizeof(ST) == 2) {
    f16x8 v = *(const f16x8*)p;
#pragma unroll
    for (int e = 0; e < 8; ++e) o[e] = (float)v[e];
  } else {
    const float4* q = (const float4*)p;
    float4 a = q[0], b = q[1];
    o[0]=a.x; o[1]=a.y; o[2]=a.z; o[3]=a.w; o[4]=b.x; o[5]=b.y; o[6]=b.z; o[7]=b.w;
  }
}

// =====================================================================
// PREP (merged): blocks [0,8192): activations f32->f16 (+zbuf init);
//                blocks [8192,9472): weight convert+transpose (5 mats).
// =====================================================================
struct PArgs {
  const float* asrc[4]; half_t* adst[4];
  const float* wsrc[5]; half_t* wdst[5];
};

__global__ __launch_bounds__(256) void prep(PArgs pa, half_t* zbuf) {
  __shared__ float T[64][65];
  const int bx = blockIdx.x, t = threadIdx.x;
  if (bx < 8192) {
    if (bx == 0 && t < 8) {
      float4 z = {0.f, 0.f, 0.f, 0.f};
      ((float4*)zbuf)[t] = z;
    }
    const int mat = bx >> 11, blk = bx & 2047;
    const float* s = pa.asrc[mat];
    half_t* d = pa.adst[mat];
    size_t i = ((size_t)blk * 256 + t) * 8;
    float4 v0 = *(const float4*)(s + i), v1 = *(const float4*)(s + i + 4);
    f16x8 h;
    h[0]=(half_t)v0.x; h[1]=(half_t)v0.y; h[2]=(half_t)v0.z; h[3]=(half_t)v0.w;
    h[4]=(half_t)v1.x; h[5]=(half_t)v1.y; h[6]=(half_t)v1.z; h[7]=(half_t)v1.w;
    *(f16x8*)(d + i) = h;
  } else {
    const int idx = bx - 8192;          // 0..1279
    const int z = idx >> 8, rem = idx & 255;
    const int k0 = (rem & 15) * 64, n0 = (rem >> 4) * 64;
    const float* W = pa.wsrc[z];
    half_t* D = pa.wdst[z];
#pragma unroll
    for (int it = 0; it < 4; ++it) {
      int id2 = t + it * 256; int r = id2 >> 4, c4 = (id2 & 15) * 4;
      float4 v = *(const float4*)(W + (size_t)(k0 + r) * DM + n0 + c4);
      T[r][c4] = v.x; T[r][c4 + 1] = v.y; T[r][c4 + 2] = v.z; T[r][c4 + 3] = v.w;
    }
    __syncthreads();
#pragma unroll
    for (int it = 0; it < 2; ++it) {
      int id2 = t + it * 256; int n = id2 >> 3, kc = (id2 & 7) * 8;
      f16x8 o;
#pragma unroll
      for (int e = 0; e < 8; ++e) o[e] = (half_t)T[kc + e][n];
      *(f16x8*)&D[(size_t)(n0 + n) * DM + k0 + kc] = o;
    }
  }
}

// =====================================================================
// GEMM: C[M,1024] = A[M,1024](f16) @ Wt[n][k]^T ; z-indexed operand sets.
// Single-buffered staging, 32 KB LDS.
// =====================================================================
struct GArgs {
  const half_t* A[4];  const half_t* Bt[4];
  const float* ba[4]; const float* bu[4]; const float* bv[4];
  half_t* oa[4]; half_t* ob[4]; float* of[4];
};

template<bool F32OUT>
__global__ __launch_bounds__(256) void gemm_k(GArgs g, int K) {
  __shared__ __align__(16) half_t At[128 * 64];
  __shared__ __align__(16) half_t Bt[128 * 64];
  const int z = blockIdx.z;
  const half_t* A = g.A[z];
  const half_t* B = g.Bt[z];
  const int n0 = blockIdx.x * 128, m0 = blockIdx.y * 128;
  const int t = threadIdx.x, w = t >> 6, lane = t & 63;
  const f32x4 zf = {0.f, 0.f, 0.f, 0.f};
  f32x4 acc[2][8];
#pragma unroll
  for (int i = 0; i < 2; ++i)
#pragma unroll
    for (int j = 0; j < 8; ++j) acc[i][j] = zf;

  for (int k0 = 0; k0 < K; k0 += 64) {
    stage_gll(At, A + (size_t)m0 * K + k0, K);
    stage_gll(Bt, B + (size_t)n0 * K + k0, K);
    __syncthreads();
    mfma_block(At, Bt, w, lane, acc);
    __syncthreads();
  }
  const int grp = lane >> 4, li = lane & 15;
#pragma unroll
  for (int fr = 0; fr < 2; ++fr)
#pragma unroll
    for (int fc = 0; fc < 8; ++fc)
#pragma unroll
      for (int r = 0; r < 4; ++r) {
        int row = m0 + w * 32 + fr * 16 + grp * 4 + r;
        int col = n0 + fc * 16 + li;
        float v = acc[fr][fc][r];
        if (g.ba[z]) v += g.ba[z][col];
        if constexpr (F32OUT) {
          g.of[z][(size_t)row * DM + col] = v;
        } else {
          float v1 = v + (g.bu[z] ? g.bu[z][col] : 0.f);
          g.oa[z][(size_t)row * DM + col] = (half_t)v1;
          if (g.ob[z]) g.ob[z][(size_t)row * DM + col] = (half_t)(v + g.bv[z][col]);
        }
      }
}

// =====================================================================
// V transpose per head: vp[b*S+s][h*64+d] -> vT[bh][d][s]  (f16)
// =====================================================================
__global__ __launch_bounds__(256) void vtrans(const half_t* vp, half_t* vT) {
  __shared__ half_t T[64][72];
  const int s0 = blockIdx.x * 64, h = blockIdx.y, b = blockIdx.z;
  const int t = threadIdx.x;
#pragma unroll
  for (int it = 0; it < 2; ++it) {
    int idx = t + it * 256; int s = idx >> 3, c = idx & 7;
    uint4 v = *(const uint4*)(vp + ((size_t)(b * S_LEN + s0 + s)) * DM + h * DH + c * 8);
    *(uint4*)&T[s][c * 8] = v;
  }
  __syncthreads();
  half_t* dst = vT + ((size_t)(b * NH + h)) * DH * S_LEN;
#pragma unroll
  for (int it = 0; it < 2; ++it) {
    int idx = t + it * 256; int d = idx >> 3, sc = (idx & 7) * 8;
    f16x8 o;
#pragma unroll
    for (int e = 0; e < 8; ++e) o[e] = T[sc + e][d];
    *(f16x8*)&dst[(size_t)d * S_LEN + s0 + sc] = o;
  }
}

// =====================================================================
// FUSED scores v2: writes EXP(s) once (f16), s = (content+shifted pos)/32,
// + per-(row, k-tile) sumexp partials (max-free: |s| <~ 3).
//
// TXL shift identity (local q,k in [0,128), base = 1920 + k0 - i0):
//   e = k - q + 127; jv = base + e; dlt(e) = (jv >= S+1); j = jv mod (S+1)
//   rel[q,k] = qv[i0+q+dlt] . p[j]   (j==S is a zero row)
//
// WRITER-SIDE SHEAR: dlt depends only on e, so the band-MFMA writer at
// (rM, e) computes its unique consumer (q = rM - dlt(e), k = e + q - 127)
// and writes straight into Ms[q][k] (pitch 132 -> grp-disjoint banks).
// No Pb staging (bm fragments load global->reg, L2-resident).
// LDS = Ms 33,792 B (aliases QU|Kt) + QV 16,384 B = 50,176 B
//   -> 3 blocks/CU (24 waves, 6/SIMD) with __launch_bounds__(512,6).
// =====================================================================
template<typename ST>
__global__ __launch_bounds__(512, 6) void score_fused(
    const half_t* __restrict__ qu_, const half_t* __restrict__ qv_,
    const half_t* __restrict__ kp_, const half_t* __restrict__ pp_,
    const half_t* __restrict__ zbuf, ST* __restrict__ sc, float* __restrict__ part)
{
  __shared__ __align__(16) half_t MsR[16896];   // 33,792 B
  __shared__ __align__(16) half_t QV[128 * 64]; // 16 KB
  half_t* QU = MsR;                             // phase 1
  half_t* Kt = MsR + 8192;
  half_t* Ms = MsR;                             // phase 2: [128][132] f16

  const int bh = blockIdx.z, b = bh >> 4, h = bh & 15;
  const int kt = blockIdx.x, qt = blockIdx.y;
  const int i0 = qt * 128, k0 = kt * 128;
  const int base = 1920 + k0 - i0;              // in [0,3840]
  const int t = threadIdx.x, w = t >> 6, lane = t & 63;
  const int grp = lane >> 4, li = lane & 15;

  // ---- stage QU, Kt, QV (128x64 each; swizzled global src) ----
  {
    const half_t* srcA = qu_ + ((size_t)(b * S_LEN + i0)) * DM + h * DH;
    const half_t* srcB = kp_ + ((size_t)(b * S_LEN + k0)) * DM + h * DH;
    const half_t* srcQ = qv_ + ((size_t)(b * S_LEN + i0)) * DM + h * DH;
#pragma unroll
    for (int p = 0; p < 2; ++p) {
      int cidx = t + p * 512; int r = cidx >> 3, c = cidx & 7;
      size_t off = (size_t)r * DM + ((c ^ (r & 7)) << 3);
      gll16(srcA + off, QU + (size_t)cidx * 8);
      gll16(srcB + off, Kt + (size_t)cidx * 8);
      gll16(srcQ + off, QV + (size_t)cidx * 8);
    }
  }

  // ---- band B-fragments: global -> registers (rows jv(e), zero row) ----
  const int e0 = w * 16 + li, e1 = (w + 8) * 16 + li;
  const int dlt0 = (base + e0 >= S_LEN + 1) ? 1 : 0;
  const int dlt1 = (base + e1 >= S_LEN + 1) ? 1 : 0;
  f16x8 bm[2][2];
#pragma unroll
  for (int eci = 0; eci < 2; ++eci) {
    int e_row = eci ? e1 : e0;
    int jv = base + e_row; if (jv >= S_LEN + 1) jv -= (S_LEN + 1);
    const half_t* srcp = (jv == S_LEN) ? zbuf
        : pp_ + ((size_t)(b * S_LEN + jv)) * DM + h * DH;
#pragma unroll
    for (int kk = 0; kk < 2; ++kk)
      bm[kk][eci] = *(const f16x8*)(srcp + (kk * 4 + grp) * 8);
  }
  __syncthreads();

  // ---- content MFMA: wave w owns q rows [w*16, w*16+16) ----
  const f32x4 zf = {0.f, 0.f, 0.f, 0.f};
  f32x4 acc_c[8];
#pragma unroll
  for (int j = 0; j < 8; ++j) acc_c[j] = zf;
#pragma unroll
  for (int kk = 0; kk < 2; ++kk) {
    const int chunk = kk * 4 + grp;
    int ra = w * 16 + li;
    f16x8 a = *(const f16x8*)&QU[(size_t)(ra * 8 + (chunk ^ (ra & 7))) * 8];
#pragma unroll
    for (int fc = 0; fc < 8; ++fc) {
      int rb = fc * 16 + li;
      f16x8 bf = *(const f16x8*)&Kt[(size_t)(rb * 8 + (chunk ^ (rb & 7))) * 8];
      acc_c[fc] = __builtin_amdgcn_mfma_f32_16x16x32_f16(a, bf, acc_c[fc], 0, 0, 0);
    }
  }
  __syncthreads();   // QU/Kt reads done; region now writable as Ms

  // ---- band MFMA rf=0..7, writer-side shear into Ms[q][k] ----
  for (int rf = 0; rf < 8; ++rf) {
    f32x4 am[2] = {zf, zf};
#pragma unroll
    for (int kk = 0; kk < 2; ++kk) {
      int ra = rf * 16 + li;
      f16x8 a = *(const f16x8*)&QV[(size_t)(ra * 8 + ((kk * 4 + grp) ^ (ra & 7))) * 8];
      am[0] = __builtin_amdgcn_mfma_f32_16x16x32_f16(a, bm[kk][0], am[0], 0, 0, 0);
      am[1] = __builtin_amdgcn_mfma_f32_16x16x32_f16(a, bm[kk][1], am[1], 0, 0, 0);
    }
#pragma unroll
    for (int eci = 0; eci < 2; ++eci) {
      int e = eci ? e1 : e0;
      int dlt = eci ? dlt1 : dlt0;
#pragma unroll
      for (int r = 0; r < 4; ++r) {
        int rM = rf * 16 + grp * 4 + r;
        int q = rM - dlt;
        int k = e + q - 127;
        if ((unsigned)q < 128u && (unsigned)k < 128u)
          Ms[q * 132 + k] = (half_t)am[eci][r];
      }
    }
  }

  // ---- 9th row-frag (rM=128 -> q=127, needs dlt(e)==1, e<128) ----
  {
    f16x8 aq0, aq1;                              // lazy load: short live range
    {
      int r128 = i0 + 128; if (r128 > S_LEN - 1) r128 = S_LEN - 1;
      const half_t* q128p = qv_ + ((size_t)(b * S_LEN + r128)) * DM + h * DH;
      aq0 = *(const f16x8*)(q128p + (0 * 4 + grp) * 8);
      aq1 = *(const f16x8*)(q128p + (1 * 4 + grp) * 8);
    }
    f32x4 am0 = zf;
    am0 = __builtin_amdgcn_mfma_f32_16x16x32_f16(aq0, bm[0][0], am0, 0, 0, 0);
    am0 = __builtin_amdgcn_mfma_f32_16x16x32_f16(aq1, bm[1][0], am0, 0, 0, 0);
    if (grp == 0 && dlt0 == 1)                   // e0 < 128 always (w<8)
      Ms[127 * 132 + e0] = (half_t)am0[0];
  }
  __syncthreads();

  // ---- combine: s = (content + Ms[q][k])/32; exp; write; partials ----
  ST* sb = sc + (size_t)bh * S2;
  float lsum[4] = {0.f, 0.f, 0.f, 0.f};
#pragma unroll
  for (int fc = 0; fc < 8; ++fc) {
#pragma unroll
    for (int rr = 0; rr < 4; ++rr) {
      int q = w * 16 + grp * 4 + rr;
      int k = fc * 16 + li;
      float mval = (float)Ms[q * 132 + k];
      float s = (acc_c[fc][rr] + mval) * 0.03125f;
      float ev = __expf(s);
      sb[(size_t)(i0 + q) * S_LEN + k0 + k] = (ST)ev;
      lsum[rr] += ev;
    }
  }
#pragma unroll
  for (int rr = 0; rr < 4; ++rr) {
    float v = lsum[rr];
#pragma unroll
    for (int d = 1; d < 16; d <<= 1) v += __shfl_xor(v, d);
    if (li == 0)
      part[((size_t)bh * S_LEN + i0 + w * 16 + grp * 4 + rr) * 16 + kt] = v;
  }
}

// =====================================================================
// Pass 3: combine sumexp partials -> 1/L; stream exp tiles, scale by 1/L,
// write final f32 attn ONCE, and MFMA p@V -> ctx (f16).
// V staging double-buffered. In-place safe for ST=float.
// =====================================================================
template<typename ST>
__global__ __launch_bounds__(256) void av_attn(const ST* sc, const half_t* vT, const float* part,
                                               float* attn, half_t* ctx) {
  __shared__ __align__(16) half_t Vt[2][64 * 128];
  __shared__ float Ls[128];
  const int bh = blockIdx.y, b = bh >> 4, h = bh & 15;
  const int q0 = blockIdx.x * 128;
  const int t = threadIdx.x;
  if (t < 128) {
    const float* pp = part + ((size_t)bh * S_LEN + q0 + t) * 16;
    float L = 0.f;
#pragma unroll
    for (int k = 0; k < 16; ++k) L += pp[k];
    Ls[t] = 1.f / L;
  }
  const ST* sb = sc + (size_t)bh * S2;
  float* ab = attn + (size_t)bh * S2;
  const half_t* vb = vT + (size_t)bh * (DH * S_LEN);
  const int w = t >> 6, lane = t & 63, grp = lane >> 4, li = lane & 15;
  const int c1 = lane & 15, d4 = lane >> 4;
  const f32x4 zf = {0.f, 0.f, 0.f, 0.f};
  f32x4 acc[2][4];
#pragma unroll
  for (int i = 0; i < 2; ++i)
#pragma unroll
    for (int j = 0; j < 4; ++j) acc[i][j] = zf;

  // prologue stage kt=0
#pragma unroll
  for (int it = 0; it < 4; ++it) {
    int d = w * 16 + it * 4 + d4;
    gll16(vb + (size_t)d * S_LEN + ((c1 ^ (d & 15)) << 3), Vt[0] + (size_t)w * 2048 + it * 512);
  }
  __syncthreads();
  int cur = 0;

  for (int kt = 0; kt < 16; ++kt) {
    if (kt + 1 < 16) {
#pragma unroll
      for (int it = 0; it < 4; ++it) {
        int d = w * 16 + it * 4 + d4;
        gll16(vb + (size_t)d * S_LEN + (kt + 1) * 128 + ((c1 ^ (d & 15)) << 3),
              Vt[cur ^ 1] + (size_t)w * 2048 + it * 512);
      }
    }
#pragma unroll
    for (int ks = 0; ks < 4; ++ks) {
      f16x8 pa[2];
#pragma unroll
      for (int fr = 0; fr < 2; ++fr) {
        int r128 = w * 32 + fr * 16 + li;
        int row = q0 + r128;
        int col = kt * 128 + ks * 32 + grp * 8;
        float sv[8];
        load8s(&sb[(size_t)row * S_LEN + col], sv);
        float rL = Ls[r128];
#pragma unroll
        for (int e = 0; e < 8; ++e) sv[e] *= rL;
        float4* dst = (float4*)&ab[(size_t)row * S_LEN + col];
        float4 w0 = {sv[0], sv[1], sv[2], sv[3]};
        float4 w1 = {sv[4], sv[5], sv[6], sv[7]};
        dst[0] = w0; dst[1] = w1;
        f16x8 ph;
#pragma unroll
        for (int e = 0; e < 8; ++e) ph[e] = (half_t)sv[e];
        pa[fr] = ph;
      }
      f16x8 bf[4];
#pragma unroll
      for (int fc = 0; fc < 4; ++fc) {
        int d = fc * 16 + li; int chunk = ks * 4 + grp;
        bf[fc] = *(const f16x8*)&Vt[cur][(size_t)(d * 16 + (chunk ^ (d & 15))) * 8];
      }
#pragma unroll
      for (int fr = 0; fr < 2; ++fr)
#pragma unroll
        for (int fc = 0; fc < 4; ++fc)
          acc[fr][fc] = __builtin_amdgcn_mfma_f32_16x16x32_f16(pa[fr], bf[fc], acc[fr][fc], 0, 0, 0);
    }
    __syncthreads();   // drains stage of kt+1; one barrier/iter
    cur ^= 1;
  }
#pragma unroll
  for (int fr = 0; fr < 2; ++fr)
#pragma unroll
    for (int fc = 0; fc < 4; ++fc)
#pragma unroll
      for (int r = 0; r < 4; ++r) {
        int q = q0 + w * 32 + fr * 16 + grp * 4 + r;
        int d = fc * 16 + li;
        ctx[((size_t)(b * S_LEN + q)) * DM + h * DH + d] = (half_t)acc[fr][fc][r];
      }
}

// =====================================================================
extern "C" void kernel_launch(void* const* d_in, const int* in_sizes, int n_in,
                              void* d_out, int out_size, void* d_ws, size_t ws_size,
                              hipStream_t stream) {
  (void)in_sizes; (void)n_in; (void)out_size;

  const float* query  = (const float*)d_in[0];
  const float* key    = (const float*)d_in[1];
  const float* value  = (const float*)d_in[2];
  const float* pos    = (const float*)d_in[3];
  const float* Wq     = (const float*)d_in[4];
  const float* bq     = (const float*)d_in[5];
  const float* Wk     = (const float*)d_in[6];
  const float* bk     = (const float*)d_in[7];
  const float* Wv     = (const float*)d_in[8];
  const float* bv     = (const float*)d_in[9];
  const float* Wpos   = (const float*)d_in[10];
  const float* u_bias = (const float*)d_in[11];  // [16,64] == flat [1024]
  const float* v_bias = (const float*)d_in[12];
  const float* Wout   = (const float*)d_in[13];
  const float* bout   = (const float*)d_in[14];

  float* out  = (float*)d_out;
  float* attn = out + (size_t)BATCH * S_LEN * DM;

  char* ws = (char*)d_ws;
  half_t* Wt   = (half_t*)(ws);                 // 5 x 1024x1024 f16 = 10,485,760 B
  half_t* Af16 = (half_t*)(ws + 10485760);      // 4 x 8,388,608 B (dead after proj)
  float*  part = (float*)(ws + 10485760);       // 4 MB, aliases Af16[0] post-proj
  half_t* qu   = (half_t*)(ws + 44040192);
  half_t* qv   = (half_t*)(ws + 52428800);
  half_t* kp   = (half_t*)(ws + 60817408);
  half_t* pp   = (half_t*)(ws + 69206016);
  half_t* vp   = (half_t*)(ws + 77594624);
  half_t* vT   = (half_t*)(ws + 85983232);
  half_t* ctx  = (half_t*)(ws + 77594624);      // alias vp (dead after vtrans)
  half_t* zbuf = (half_t*)(ws + 94371840);      // 128 B zero row
  half_t* scH  = (half_t*)(ws + 94375936);      // 268,435,456 B if it fits
  const bool fast = ws_size >= (size_t)94375936 + (size_t)BATCH * NH * S2 * 2;

  dim3 blk(256);

  // 0. prep: activations -> f16 + zbuf init + weights -> f16 transposed
  PArgs pa;
  pa.asrc[0] = query; pa.asrc[1] = key; pa.asrc[2] = value; pa.asrc[3] = pos;
  for (int i = 0; i < 4; ++i) pa.adst[i] = Af16 + (size_t)i * CTXSZ;
  pa.wsrc[0] = Wq; pa.wsrc[1] = Wk; pa.wsrc[2] = Wv; pa.wsrc[3] = Wpos; pa.wsrc[4] = Wout;
  for (int i = 0; i < 5; ++i) pa.wdst[i] = Wt + (size_t)i * DM * DM;
  prep<<<dim3(8192 + 1280), blk, 0, stream>>>(pa, zbuf);

  // 1. projections (q dual-output with u/v biases, k, v, p) in one launch
  GArgs ga{};
  for (int i = 0; i < 4; ++i) {
    ga.A[i]  = Af16 + (size_t)i * CTXSZ;
    ga.Bt[i] = Wt + (size_t)i * DM * DM;
  }
  ga.ba[0] = bq; ga.ba[1] = bk; ga.ba[2] = bv; ga.ba[3] = nullptr;
  ga.bu[0] = u_bias; ga.bv[0] = v_bias;
  ga.oa[0] = qu; ga.oa[1] = kp; ga.oa[2] = vp; ga.oa[3] = pp;
  ga.ob[0] = qv;
  gemm_k<false><<<dim3(8, 32, 4), blk, 0, stream>>>(ga, DM);

  // 2. V -> per-head transposed [bh][d][s]
  vtrans<<<dim3(32, 16, 2), blk, 0, stream>>>(vp, vT);

  // 3. fused scores (writer-shear), 4. attn + PV
  dim3 g_sc(16, 16, 32);
  dim3 blk5(512);
  if (fast) {
    score_fused<half_t><<<g_sc, blk5, 0, stream>>>(qu, qv, kp, pp, zbuf, scH, part);
    av_attn<half_t><<<dim3(16, 32), blk, 0, stream>>>(scH, vT, part, attn, ctx);
  } else {
    float* scF = attn;  // f32 exp-scores in-place in the attn output region
    score_fused<float><<<g_sc, blk5, 0, stream>>>(qu, qv, kp, pp, zbuf, scF, part);
    av_attn<float><<<dim3(16, 32), blk, 0, stream>>>(scF, vT, part, attn, ctx);
  }

  // 5. out = ctx @ Wout^T + bout  (f32 output)
  GArgs go{};
  go.A[0] = ctx; go.Bt[0] = Wt + (size_t)4 * DM * DM;
  go.ba[0] = bout; go.of[0] = out;
  gemm_k<true><<<dim3(8, 32, 1), blk, 0, stream>>>(go, DM);
}